// Round 9
// baseline (249.695 us; speedup 1.0000x reference)
//
#include <hip/hip_runtime.h>

#define N_NODES 50000
#define N_EDGES 1600000
#define DIM 64
#define NBK 196          // buckets of 256 dst-nodes
#define BIN_BLOCKS 1563  // ceil(1.6M / 1024) -- R22: small blocks for occupancy
#define CSR_CAP 12288    // per-bucket slots = 8 octants x OCT_CAP
#define OCT_CAP 1536     // per-(bucket,octant) slots (mean ~1021, +16 sigma)
#define QCAP 3072        // per-quarter slots (mult-16-padded mean ~2560, ~8-sigma margin)
#define G1_BLOCKS 391    // gemm1: 391*128 = 50048 >= 50001 nodes (incl. dummy)
#define NB_AGG8 6250     // agg_fuse1 blocks (8 nodes/block)
#define NB_AGGH 6250     // agg_out_h blocks: 2 halves x 3125 chunks of 16 nodes
#define PLANE2 ((size_t)(N_NODES + 1) * 32)   // ushorts per T2 half-plane (3.2MB)

// f32 -> bf16 round-to-nearest-even
__device__ __forceinline__ unsigned short f2bf(float f) {
    union { float f; unsigned u; } v; v.f = f;
    unsigned r = v.u + 0x7FFF + ((v.u >> 16) & 1);
    return (unsigned short)(r >> 16);
}
__device__ __forceinline__ float bf2f(unsigned short h) {
    union { unsigned u; float f; } v; v.u = ((unsigned)h) << 16;  return v.f;
}
// packed-bf16 halves of a uint -> f32 (low ushort, high ushort)
__device__ __forceinline__ float blo(unsigned u) {
    union { unsigned u; float f; } v; v.u = u << 16; return v.f;
}
__device__ __forceinline__ float bhi(unsigned u) {
    union { unsigned u; float f; } v; v.u = u & 0xFFFF0000u; return v.f;
}

// R22: binning with 1024 edges/block (was 4096). R21 isolated bin_edges at
// ~40us with 1.5 blocks/CU -- latency-exposed serial chain, not atomics (R20)
// and not BW (FETCH 12.6MB). 1563 blocks x 4 edges/thread: ~30 VGPR, 8.5KB
// LDS -> ~6 co-resident blocks/CU overlap each other's load/atomic/scan
// latencies. Oct-split kept (oct = blk&7; ~195 blocks/counter -- R20 showed
// contention depth doesn't matter).
__global__ __launch_bounds__(256) void bin_edges(const int* __restrict__ src,
                                                 const int* __restrict__ dst,
                                                 int* __restrict__ bcur,
                                                 int* __restrict__ binned) {
    __shared__ int cnt[NBK];
    __shared__ int lofs[NBK];
    __shared__ int shiftv[NBK];
    __shared__ int sb[256];
    __shared__ int stag[1024];
    __shared__ unsigned char stb[1024];
    int tid = threadIdx.x;

    if (tid < NBK) cnt[tid] = 0;
    __syncthreads();

    int base = blockIdx.x * 1024;
    int oct = blockIdx.x & 7;
    int nedge = N_EDGES - base;
    if (nedge > 1024) nedge = 1024;

    int myb[4], myr[4], myp[4];
#pragma unroll
    for (int i = 0; i < 4; ++i) {
        int e = base + i * 256 + tid;
        myb[i] = -1;
        if (e < N_EDGES) {
            int s = src[e], d = dst[e];
            int b = d >> 8;
            myb[i] = b;
            myp[i] = ((d & 255) << 16) | s;
            myr[i] = atomicAdd(&cnt[b], 1);
        }
    }
    __syncthreads();

    int c = (tid < NBK) ? cnt[tid] : 0;
    sb[tid] = c;
    __syncthreads();
    for (int off = 1; off < 256; off <<= 1) {
        int u = (tid >= off) ? sb[tid - off] : 0;
        __syncthreads();
        sb[tid] += u;
        __syncthreads();
    }
    if (tid < NBK) {
        lofs[tid] = sb[tid] - c;
        if (c) shiftv[tid] = tid * CSR_CAP + oct * OCT_CAP
                           + atomicAdd(&bcur[(tid * 8 + oct) * 16], c) - lofs[tid];
    }
    __syncthreads();

#pragma unroll
    for (int i = 0; i < 4; ++i) {
        if (myb[i] >= 0) {
            int idx = lofs[myb[i]] + myr[i];
            stag[idx] = myp[i];
            stb[idx] = (unsigned char)myb[i];
        }
    }
    __syncthreads();

    for (int i = tid; i < nedge; i += 256)
        binned[i + shiftv[stb[i]]] = stag[i];
}

// R21-verbatim gemm1: T = feat @ W1^T (bf16). lane = output feature; W1 row
// in registers; X staged in LDS, read as wave-uniform broadcasts; 4 nodes in
// flight. 391 blocks x 128 nodes. Writes dummy zero row at node == N_NODES.
__global__ __launch_bounds__(256) void gemm1(const float* __restrict__ X,
                                             const float* __restrict__ W,
                                             unsigned short* __restrict__ T) {
    __shared__ __align__(16) float4 xs[128 * 16];   // 32 KB: 128 node rows
    int tid = threadIdx.x;
    int w = tid >> 6, lane = tid & 63;
    int nbase = blockIdx.x * 128;

    float4 wreg[16];
    const float4* wp = (const float4*)(W + lane * 64);
#pragma unroll
    for (int k4 = 0; k4 < 16; ++k4) wreg[k4] = wp[k4];

    const float4* xg = (const float4*)X;
    for (int L = tid; L < 2048; L += 256) {
        int row = nbase + (L >> 4);
        float4 v = {0.f, 0.f, 0.f, 0.f};
        if (row < N_NODES) v = xg[(size_t)row * 16 + (L & 15)];
        xs[L] = v;
    }
    __syncthreads();

    for (int g = 0; g < 8; ++g) {
        int n0 = w * 32 + g * 4;
        float accA = 0.f, accB = 0.f, accC = 0.f, accD = 0.f;
#pragma unroll
        for (int k4 = 0; k4 < 16; ++k4) {
            float4 w4 = wreg[k4];
            float4 xA = xs[(n0 + 0) * 16 + k4];
            float4 xB = xs[(n0 + 1) * 16 + k4];
            float4 xC = xs[(n0 + 2) * 16 + k4];
            float4 xD = xs[(n0 + 3) * 16 + k4];
            accA += xA.x * w4.x + xA.y * w4.y + xA.z * w4.z + xA.w * w4.w;
            accB += xB.x * w4.x + xB.y * w4.y + xB.z * w4.z + xB.w * w4.w;
            accC += xC.x * w4.x + xC.y * w4.y + xC.z * w4.z + xC.w * w4.w;
            accD += xD.x * w4.x + xD.y * w4.y + xD.z * w4.z + xD.w * w4.w;
        }
        int gn = nbase + n0;
        unsigned short vA = (gn + 0 == N_NODES) ? (unsigned short)0 : f2bf(accA);
        unsigned short vB = (gn + 1 == N_NODES) ? (unsigned short)0 : f2bf(accB);
        unsigned short vC = (gn + 2 == N_NODES) ? (unsigned short)0 : f2bf(accC);
        unsigned short vD = (gn + 3 == N_NODES) ? (unsigned short)0 : f2bf(accD);
        if (gn + 0 <= N_NODES) T[(size_t)(gn + 0) * 64 + lane] = vA;
        if (gn + 1 <= N_NODES) T[(size_t)(gn + 1) * 64 + lane] = vB;
        if (gn + 2 <= N_NODES) T[(size_t)(gn + 2) * 64 + lane] = vC;
        if (gn + 3 <= N_NODES) T[(size_t)(gn + 3) * 64 + lane] = vD;
    }
}

// R20-verbatim build_csr: one workgroup per (bucket, dst-quarter); scans the
// bucket's 8 octant regions; per-node pad-tail writes.
__global__ __launch_bounds__(256) void build_csr(const int* __restrict__ binned,
                                                 const int* __restrict__ bcur,
                                                 unsigned* __restrict__ nodeinfo,
                                                 unsigned short* __restrict__ csr16) {
    __shared__ int cnt[64], cnt2[64], ofs[64], sb[64];
    __shared__ int mo[8];
    int tid = threadIdx.x;
    int b = blockIdx.x >> 2;
    int q = blockIdx.x & 3;
    int qbase = (b * 4 + q) * QCAP;
    if (tid < 64) { cnt[tid] = 0; cnt2[tid] = 0; }
    if (tid < 8) {
        int m = bcur[(b * 8 + tid) * 16];
        mo[tid] = m > OCT_CAP ? OCT_CAP : m;
    }
    __syncthreads();

    for (int oct = 0; oct < 8; ++oct) {
        int ibase = b * CSR_CAP + oct * OCT_CAP;
        int m = mo[oct];
        for (int i = tid; i < m; i += 256) {
            int dl = (binned[ibase + i] >> 16) & 255;
            if ((dl >> 6) == q) atomicAdd(&cnt[dl & 63], 1);
        }
    }
    __syncthreads();

    int v = 0, myc = 0;
    if (tid < 64) { myc = cnt[tid]; v = (myc + 15) & ~15; sb[tid] = v; }  // mult-16 pad
    __syncthreads();
    for (int off = 1; off < 64; off <<= 1) {
        int u = (tid >= off && tid < 64) ? sb[tid - off] : 0;
        __syncthreads();
        if (tid < 64) sb[tid] += u;
        __syncthreads();
    }
    if (tid < 64) {
        int o = sb[tid] - v;
        ofs[tid] = o;
        int node = (b << 8) + (q << 6) + tid;
        if (node < N_NODES)
            nodeinfo[node] = ((unsigned)v << 23) | (unsigned)(qbase + o);
        for (int i = myc; i < v; ++i)          // pad tail with dummy src
            csr16[qbase + o + i] = (unsigned short)N_NODES;
    }
    __syncthreads();

    for (int oct = 0; oct < 8; ++oct) {
        int ibase = b * CSR_CAP + oct * OCT_CAP;
        int m = mo[oct];
        for (int i = tid; i < m; i += 256) {
            int p = binned[ibase + i];
            int dl = (p >> 16) & 255;
            if ((dl >> 6) == q) {
                int r = atomicAdd(&cnt2[dl & 63], 1);
                csr16[qbase + ofs[dl & 63] + r] = (unsigned short)(p & 0xFFFF);
            }
        }
    }
}

// Accumulate one uint4 (8 bf16 feature values) into 8 f32 accumulators.
#define ACC8(d)                                                     \
    a0 += blo(d.x); a1 += bhi(d.x); a2 += blo(d.y); a3 += bhi(d.y); \
    a4 += blo(d.z); a5 += bhi(d.z); a6 += blo(d.w); a7 += bhi(d.w);

// R17-verbatim agg_fuse1 except T2 is written as TWO HALF-PLANES (R22) for
// agg_out_h's L2-resident gather. Full-row T gather + fused W2 epilogue kept.
__global__ __launch_bounds__(512) void agg_fuse1(const unsigned short* __restrict__ T,
                                                 const unsigned short* __restrict__ csr,
                                                 const unsigned* __restrict__ nodeinfo,
                                                 const float* __restrict__ b1,
                                                 const float* __restrict__ W2,
                                                 unsigned short* __restrict__ T2) {
    __shared__ __align__(16) float4 W2t4[1024];     // 16 KB (W2 transposed, lane-striped)
    __shared__ __align__(16) float part[8][8][72];  // 18 KB (per-wave partials; row0 doubles as h)
    int tid = threadIdx.x;
    int w = tid >> 6;
    int lane = tid & 63;
    int g8 = lane >> 3;
    int fs = lane & 7;
    int node = blockIdx.x * 8 + w;

    for (int L4 = tid; L4 < 1024; L4 += 512) {
        int k4 = L4 >> 6, f = L4 & 63;
        W2t4[L4] = *(const float4*)(W2 + f * 64 + k4 * 4);
    }

    unsigned info = __builtin_nontemporal_load(nodeinfo + node);
    float bias = b1[lane];
    int pos = (int)(info & 0x7FFFFFu);
    int nch = (int)(info >> 23) >> 3;   // 8-edge chunks, even (pcnt mult 16)
    const unsigned short* ip = csr + pos + g8;
    const uint4* Tp = (const uint4*)T;
    float a0 = 0.f, a1 = 0.f, a2 = 0.f, a3 = 0.f, a4 = 0.f, a5 = 0.f, a6 = 0.f, a7 = 0.f;
    int c = 0;
    for (; c + 4 <= nch; c += 4) {
        int j0 = __builtin_nontemporal_load(ip + c * 8);
        int j1 = __builtin_nontemporal_load(ip + c * 8 + 8);
        int j2 = __builtin_nontemporal_load(ip + c * 8 + 16);
        int j3 = __builtin_nontemporal_load(ip + c * 8 + 24);
        uint4 d0 = Tp[j0 * 8 + fs];
        uint4 d1 = Tp[j1 * 8 + fs];
        uint4 d2 = Tp[j2 * 8 + fs];
        uint4 d3 = Tp[j3 * 8 + fs];
        ACC8(d0) ACC8(d1) ACC8(d2) ACC8(d3)
    }
    if (c < nch) {   // remaining 2 chunks (nch even)
        int j0 = __builtin_nontemporal_load(ip + c * 8);
        int j1 = __builtin_nontemporal_load(ip + c * 8 + 8);
        uint4 d0 = Tp[j0 * 8 + fs];
        uint4 d1 = Tp[j1 * 8 + fs];
        ACC8(d0) ACC8(d1)
    }
    float4 pa = {a0, a1, a2, a3};
    float4 pb = {a4, a5, a6, a7};
    *(float4*)&part[w][g8][fs * 8] = pa;
    *(float4*)&part[w][g8][fs * 8 + 4] = pb;
    __syncthreads();   // covers W2t4 staging (part is wave-private)

    float acc = bias;
#pragma unroll
    for (int g = 0; g < 8; ++g) acc += part[w][g][lane];

    float e = __expf(2.f * acc);
    part[w][0][lane] = 1.f - 2.f / (e + 1.f);   // after all part reads (lockstep wave)

    const float* hrow = &part[w][0][0];
    float tf = 0.f;
#pragma unroll
    for (int k4 = 0; k4 < 16; ++k4) {
        float4 hv = *(const float4*)(hrow + k4 * 4);   // broadcast
        float4 wv = W2t4[k4 * 64 + lane];
        tf += hv.x * wv.x + hv.y * wv.y + hv.z * wv.z + hv.w * wv.w;
    }
    // half-plane write: plane = lane>>5, col = lane&31 (64B contiguous per half)
    T2[(size_t)(lane >> 5) * PLANE2 + (size_t)node * 32 + (lane & 31)] = f2bf(tf);

    // zero T2's dummy pad row in both planes (block 0 only)
    if (blockIdx.x == 0 && tid < 64)
        T2[(size_t)(tid >> 5) * PLANE2 + (size_t)N_NODES * 32 + (tid & 31)] = 0;
}

// R22: layer-2 aggregate over HALF-PLANES. h = blockIdx&1 rides the round-
// robin block->XCD dispatch: plane h (3.2MB contiguous) is touched only by
// XCDs {h,h+2,h+4,h+6} -> fully L2-resident (R19 proved pinning works; this
// time per-edge sector count is UNCHANGED: 2x64B here vs 1x128B before, so
// the R18/R19 request-inflation mistake is avoided). 16 edges per dwordx4
// load. Wave: e4 = lane>>2 (16 edge slots), fs = lane&3 (uint4 within 64B
// half-row); reduce over e4 = 4 shfl_xor rounds; lanes e4==0 write 32 f32.
__global__ __launch_bounds__(512) void agg_out_h(const unsigned short* __restrict__ T2,
                                                 const unsigned short* __restrict__ csr,
                                                 const unsigned* __restrict__ nodeinfo,
                                                 const float* __restrict__ bias,
                                                 float* __restrict__ outp) {
    int tid = threadIdx.x;
    int w = tid >> 6, lane = tid & 63;
    int e4 = lane >> 2;           // edge slot (16 per wave-load)
    int fs = lane & 3;            // uint4 column within the 64B half-row
    int h = blockIdx.x & 1;
    int c = blockIdx.x >> 1;      // 0..3124
    const uint4* Tq = (const uint4*)(T2 + (size_t)h * PLANE2);

    for (int ns = 0; ns < 2; ++ns) {
        int node = c * 16 + w * 2 + ns;
        unsigned info = __builtin_nontemporal_load(nodeinfo + node);
        int pos = (int)(info & 0x7FFFFFu);
        int nt16 = (int)(info >> 23) >> 4;    // 16-edge chunks (pcnt mult 16)
        const unsigned short* ip = csr + pos + e4;
        float a0 = 0.f, a1 = 0.f, a2 = 0.f, a3 = 0.f,
              a4 = 0.f, a5 = 0.f, a6 = 0.f, a7 = 0.f;
        int k = 0;
        for (; k + 2 <= nt16; k += 2) {
            int j0 = __builtin_nontemporal_load(ip + k * 16);
            int j1 = __builtin_nontemporal_load(ip + k * 16 + 16);
            uint4 d0 = Tq[(size_t)j0 * 4 + fs];
            uint4 d1 = Tq[(size_t)j1 * 4 + fs];
            ACC8(d0) ACC8(d1)
        }
        if (k < nt16) {
            int j0 = __builtin_nontemporal_load(ip + k * 16);
            uint4 d0 = Tq[(size_t)j0 * 4 + fs];
            ACC8(d0)
        }
        // reduce over the 16 edge slots (lane bits 2..5)
#pragma unroll
        for (int m = 4; m <= 32; m <<= 1) {
            a0 += __shfl_xor(a0, m); a1 += __shfl_xor(a1, m);
            a2 += __shfl_xor(a2, m); a3 += __shfl_xor(a3, m);
            a4 += __shfl_xor(a4, m); a5 += __shfl_xor(a5, m);
            a6 += __shfl_xor(a6, m); a7 += __shfl_xor(a7, m);
        }
        if (e4 == 0) {
            const float4* bp = (const float4*)(bias + h * 32 + fs * 8);
            float4 b0 = bp[0], b1v = bp[1];
            float* op = outp + (size_t)node * 64 + h * 32 + fs * 8;
            float4 o0 = {a0 + b0.x, a1 + b0.y, a2 + b0.z, a3 + b0.w};
            float4 o1 = {a4 + b1v.x, a5 + b1v.y, a6 + b1v.z, a7 + b1v.w};
            *(float4*)op = o0;
            *(float4*)(op + 4) = o1;
        }
    }
}

extern "C" void kernel_launch(void* const* d_in, const int* in_sizes, int n_in,
                              void* d_out, int out_size, void* d_ws, size_t ws_size,
                              hipStream_t stream) {
    const float* feat = (const float*)d_in[0];
    const int*   src  = (const int*)d_in[1];
    const int*   dst  = (const int*)d_in[2];
    const float* W1   = (const float*)d_in[3];
    const float* b1   = (const float*)d_in[4];
    const float* W2   = (const float*)d_in[5];
    const float* b2   = (const float*)d_in[6];
    float* out = (float*)d_out;

    // ws layout (~28 MB; harness poisons 256 MB of ws -> plenty)
    int*            binned   = (int*)d_ws;                                // 196*12288 ints
    unsigned short* csr16    = (unsigned short*)(binned + NBK * CSR_CAP); // 784*3072 ushort
    unsigned*       nodeinfo = (unsigned*)(csr16 + NBK * 4 * QCAP);       // 50000
    int*            bcur     = (int*)(nodeinfo + N_NODES);                // 196*8*16 ints
    unsigned short* t        = (unsigned short*)(bcur + NBK * 8 * 16 + 8); // 50001*64 bf16
    unsigned short* t2       = t + (size_t)(N_NODES + 1) * 64;            // 2 half-planes

    // ---- binning, layer-1 transform, CSR build ----
    (void)hipMemsetAsync(bcur, 0, NBK * 8 * 16 * sizeof(int), stream);
    bin_edges<<<BIN_BLOCKS, 256, 0, stream>>>(src, dst, bcur, binned);
    gemm1<<<G1_BLOCKS, 256, 0, stream>>>(feat, W1, t);
    build_csr<<<NBK * 4, 256, 0, stream>>>(binned, bcur, nodeinfo, csr16);

    // ---- Layer 1 aggregate + fused layer-2 transform: t2 = tanh(agg+b1)@W2^T ----
    agg_fuse1<<<NB_AGG8, 512, 0, stream>>>(t, csr16, nodeinfo, b1, W2, t2);

    // ---- Layer 2 aggregate over half-planes: out = agg(t2) + b2, f32 ----
    agg_out_h<<<NB_AGGH, 512, 0, stream>>>(t2, csr16, nodeinfo, b2, out);
}

// Round 10
// 220.061 us; speedup vs baseline: 1.1347x; 1.1347x over previous
//
#include <hip/hip_runtime.h>

#define N_NODES 50000
#define N_EDGES 1600000
#define DIM 64
#define NBK 196          // buckets of 256 dst-nodes
#define BIN_BLOCKS 391   // ceil(1.6M / 4096)
#define CSR_CAP 12288    // per-bucket binned slots = 8 octants x OCT_CAP
#define OCT_CAP 1536     // per-(bucket,octant) slots (mean ~1021, +16 sigma)
#define BCAP 13312       // per-bucket csr16 slots (mean 8192 + pad<=3840 + 14-sigma)
#define G1_BLOCKS 391    // gemm1 half: 391*128 = 50048 >= 50001 nodes (incl. dummy)
#define NB_AGG8 6250     // agg blocks (8 nodes/block; 6250*8 == 50000 exactly)

// f32 -> bf16 round-to-nearest-even
__device__ __forceinline__ unsigned short f2bf(float f) {
    union { float f; unsigned u; } v; v.f = f;
    unsigned r = v.u + 0x7FFF + ((v.u >> 16) & 1);
    return (unsigned short)(r >> 16);
}
__device__ __forceinline__ float bf2f(unsigned short h) {
    union { unsigned u; float f; } v; v.u = ((unsigned)h) << 16;  return v.f;
}
// packed-bf16 halves of a uint -> f32 (low ushort, high ushort)
__device__ __forceinline__ float blo(unsigned u) {
    union { unsigned u; float f; } v; v.u = u << 16; return v.f;
}
__device__ __forceinline__ float bhi(unsigned u) {
    union { unsigned u; float f; } v; v.u = u & 0xFFFF0000u; return v.f;
}

// R23: re-fused binning (R6-proven 4096-edge blocks -- R22's 1024-edge split
// regressed ~19us from per-block fixed costs) + R21's lane-parallel gemm1.
// LDS is a union: bin needs 24.5KB, gemm needs 32KB -> 32KB block.
__global__ __launch_bounds__(256) void bin_gemm1(const int* __restrict__ src,
                                                 const int* __restrict__ dst,
                                                 int* __restrict__ bcur,
                                                 int* __restrict__ binned,
                                                 const float* __restrict__ X,
                                                 const float* __restrict__ W,
                                                 unsigned short* __restrict__ T) {
    __shared__ __align__(16) char smem[32768];
    int tid = threadIdx.x;

    if (blockIdx.x >= BIN_BLOCKS) {
        // ---------------- GEMM path (R21-proven): T = X @ W^T ----------------
        float4* xs = (float4*)smem;      // 128 node rows x 16 float4 = 32KB
        int w = tid >> 6, lane = tid & 63;
        int nbase = (blockIdx.x - BIN_BLOCKS) * 128;

        float4 wreg[16];
        const float4* wp = (const float4*)(W + lane * 64);
#pragma unroll
        for (int k4 = 0; k4 < 16; ++k4) wreg[k4] = wp[k4];

        const float4* xg = (const float4*)X;
        for (int L = tid; L < 2048; L += 256) {
            int row = nbase + (L >> 4);
            float4 v = {0.f, 0.f, 0.f, 0.f};
            if (row < N_NODES) v = xg[(size_t)row * 16 + (L & 15)];
            xs[L] = v;
        }
        __syncthreads();

        for (int g = 0; g < 8; ++g) {
            int n0 = w * 32 + g * 4;
            float accA = 0.f, accB = 0.f, accC = 0.f, accD = 0.f;
#pragma unroll
            for (int k4 = 0; k4 < 16; ++k4) {
                float4 w4 = wreg[k4];
                float4 xA = xs[(n0 + 0) * 16 + k4];   // wave-uniform -> broadcast
                float4 xB = xs[(n0 + 1) * 16 + k4];
                float4 xC = xs[(n0 + 2) * 16 + k4];
                float4 xD = xs[(n0 + 3) * 16 + k4];
                accA += xA.x * w4.x + xA.y * w4.y + xA.z * w4.z + xA.w * w4.w;
                accB += xB.x * w4.x + xB.y * w4.y + xB.z * w4.z + xB.w * w4.w;
                accC += xC.x * w4.x + xC.y * w4.y + xC.z * w4.z + xC.w * w4.w;
                accD += xD.x * w4.x + xD.y * w4.y + xD.z * w4.z + xD.w * w4.w;
            }
            int gn = nbase + n0;
            unsigned short vA = (gn + 0 == N_NODES) ? (unsigned short)0 : f2bf(accA);
            unsigned short vB = (gn + 1 == N_NODES) ? (unsigned short)0 : f2bf(accB);
            unsigned short vC = (gn + 2 == N_NODES) ? (unsigned short)0 : f2bf(accC);
            unsigned short vD = (gn + 3 == N_NODES) ? (unsigned short)0 : f2bf(accD);
            if (gn + 0 <= N_NODES) T[(size_t)(gn + 0) * 64 + lane] = vA;
            if (gn + 1 <= N_NODES) T[(size_t)(gn + 1) * 64 + lane] = vB;
            if (gn + 2 <= N_NODES) T[(size_t)(gn + 2) * 64 + lane] = vC;
            if (gn + 3 <= N_NODES) T[(size_t)(gn + 3) * 64 + lane] = vD;
        }
        return;
    }

    // ---------------- Binning path (R6-proven, oct-split bcur) ----------------
    int* cnt    = (int*)smem;            // 256 ints (NBK used)
    int* lofs   = cnt + 256;
    int* shiftv = lofs + 256;
    int* sb     = shiftv + 256;
    int* stag   = sb + 256;              // 4096 ints = 16KB
    unsigned char* stb = (unsigned char*)(stag + 4096);  // 4096B

    if (tid < NBK) cnt[tid] = 0;
    __syncthreads();

    int base = blockIdx.x * 4096;
    int oct = blockIdx.x & 7;
    int nedge = N_EDGES - base;
    if (nedge > 4096) nedge = 4096;

    int myb[16], myr[16], myp[16];
#pragma unroll
    for (int i = 0; i < 16; ++i) {
        int e = base + i * 256 + tid;
        myb[i] = -1;
        if (e < N_EDGES) {
            int s = src[e], d = dst[e];
            int b = d >> 8;
            myb[i] = b;
            myp[i] = ((d & 255) << 16) | s;
            myr[i] = atomicAdd(&cnt[b], 1);
        }
    }
    __syncthreads();

    int c = (tid < NBK) ? cnt[tid] : 0;
    sb[tid] = c;
    __syncthreads();
    for (int off = 1; off < 256; off <<= 1) {
        int u = (tid >= off) ? sb[tid - off] : 0;
        __syncthreads();
        sb[tid] += u;
        __syncthreads();
    }
    if (tid < NBK) {
        lofs[tid] = sb[tid] - c;
        if (c) shiftv[tid] = tid * CSR_CAP + oct * OCT_CAP
                           + atomicAdd(&bcur[(tid * 8 + oct) * 16], c) - lofs[tid];
    }
    __syncthreads();

#pragma unroll
    for (int i = 0; i < 16; ++i) {
        if (myb[i] >= 0) {
            int idx = lofs[myb[i]] + myr[i];
            stag[idx] = myp[i];
            stb[idx] = (unsigned char)myb[i];
        }
    }
    __syncthreads();

    for (int i = tid; i < nedge; i += 256)
        binned[i + shiftv[stb[i]]] = stag[i];
}

// R23: one workgroup per BUCKET (196 blocks), all 256 dst-locals in one pass
// (was 4 quarter-blocks each scanning the full bucket: 8 effective scans ->
// 2). cnt/ofs are 256-wide; per-bucket csr region BCAP=13312 (pad-sum safe).
// nodeinfo=(pcnt<<23)|pos, pos%16==0, pcnt mult-16, dummy src = N_NODES.
__global__ __launch_bounds__(256) void build_csr(const int* __restrict__ binned,
                                                 const int* __restrict__ bcur,
                                                 unsigned* __restrict__ nodeinfo,
                                                 unsigned short* __restrict__ csr16) {
    __shared__ int cnt[256], cnt2[256], ofs[256], sb[256];
    __shared__ int mo[8];
    int tid = threadIdx.x;
    int b = blockIdx.x;
    int bbase = b * BCAP;
    cnt[tid] = 0; cnt2[tid] = 0;
    if (tid < 8) {
        int m = bcur[(b * 8 + tid) * 16];
        mo[tid] = m > OCT_CAP ? OCT_CAP : m;
    }
    __syncthreads();

    for (int oct = 0; oct < 8; ++oct) {
        int ibase = b * CSR_CAP + oct * OCT_CAP;
        int m = mo[oct];
        for (int i = tid; i < m; i += 256)
            atomicAdd(&cnt[(binned[ibase + i] >> 16) & 255], 1);
    }
    __syncthreads();

    int myc = cnt[tid];
    int v = (myc + 15) & ~15;          // mult-16 pad
    sb[tid] = v;
    __syncthreads();
    for (int off = 1; off < 256; off <<= 1) {
        int u = (tid >= off) ? sb[tid - off] : 0;
        __syncthreads();
        sb[tid] += u;
        __syncthreads();
    }
    int o = sb[tid] - v;
    ofs[tid] = o;
    int node = (b << 8) + tid;
    if (node < N_NODES)
        nodeinfo[node] = ((unsigned)v << 23) | (unsigned)(bbase + o);
    for (int i = myc; i < v; ++i)       // pad tail with dummy src
        csr16[bbase + o + i] = (unsigned short)N_NODES;
    __syncthreads();

    for (int oct = 0; oct < 8; ++oct) {
        int ibase = b * CSR_CAP + oct * OCT_CAP;
        int m = mo[oct];
        for (int i = tid; i < m; i += 256) {
            int p = binned[ibase + i];
            int dl = (p >> 16) & 255;
            int r = atomicAdd(&cnt2[dl], 1);
            csr16[bbase + ofs[dl] + r] = (unsigned short)(p & 0xFFFF);
        }
    }
}

// Accumulate one uint4 (8 bf16 feature values) into 8 f32 accumulators.
#define ACC8(d)                                                     \
    a0 += blo(d.x); a1 += bhi(d.x); a2 += blo(d.y); a3 += bhi(d.y); \
    a4 += blo(d.z); a5 += bhi(d.z); a6 += blo(d.w); a7 += bhi(d.w);

// R17-proven agg_fuse1, R23 change: idx/nodeinfo loads are PLAIN (the old
// nontemporal hint plausibly bypassed L2 -> ~900cy on the dependent idx->data
// chain; csr is 4.8MB and L2-cacheable). Gather structure untouched (three
// rounds proved it's at the per-scattered-request floor).
__global__ __launch_bounds__(512) void agg_fuse1(const unsigned short* __restrict__ T,
                                                 const unsigned short* __restrict__ csr,
                                                 const unsigned* __restrict__ nodeinfo,
                                                 const float* __restrict__ b1,
                                                 const float* __restrict__ W2,
                                                 unsigned short* __restrict__ T2) {
    __shared__ __align__(16) float4 W2t4[1024];     // 16 KB (W2 transposed, lane-striped)
    __shared__ __align__(16) float part[8][8][72];  // 18 KB (per-wave partials; row0 doubles as h)
    int tid = threadIdx.x;
    int w = tid >> 6;
    int lane = tid & 63;
    int g8 = lane >> 3;
    int fs = lane & 7;
    int node = blockIdx.x * 8 + w;

    for (int L4 = tid; L4 < 1024; L4 += 512) {
        int k4 = L4 >> 6, f = L4 & 63;
        W2t4[L4] = *(const float4*)(W2 + f * 64 + k4 * 4);
    }

    unsigned info = nodeinfo[node];
    float bias = b1[lane];
    int pos = (int)(info & 0x7FFFFFu);
    int nch = (int)(info >> 23) >> 3;   // 8-edge chunks, even (pcnt mult 16)
    const unsigned short* ip = csr + pos + g8;
    const uint4* Tp = (const uint4*)T;
    float a0 = 0.f, a1 = 0.f, a2 = 0.f, a3 = 0.f, a4 = 0.f, a5 = 0.f, a6 = 0.f, a7 = 0.f;
    int c = 0;
    for (; c + 4 <= nch; c += 4) {
        int j0 = ip[c * 8];
        int j1 = ip[c * 8 + 8];
        int j2 = ip[c * 8 + 16];
        int j3 = ip[c * 8 + 24];
        uint4 d0 = Tp[j0 * 8 + fs];
        uint4 d1 = Tp[j1 * 8 + fs];
        uint4 d2 = Tp[j2 * 8 + fs];
        uint4 d3 = Tp[j3 * 8 + fs];
        ACC8(d0) ACC8(d1) ACC8(d2) ACC8(d3)
    }
    if (c < nch) {   // remaining 2 chunks (nch even)
        int j0 = ip[c * 8];
        int j1 = ip[c * 8 + 8];
        uint4 d0 = Tp[j0 * 8 + fs];
        uint4 d1 = Tp[j1 * 8 + fs];
        ACC8(d0) ACC8(d1)
    }
    float4 pa = {a0, a1, a2, a3};
    float4 pb = {a4, a5, a6, a7};
    *(float4*)&part[w][g8][fs * 8] = pa;
    *(float4*)&part[w][g8][fs * 8 + 4] = pb;
    __syncthreads();   // covers W2t4 staging (part is wave-private)

    float acc = bias;
#pragma unroll
    for (int g = 0; g < 8; ++g) acc += part[w][g][lane];

    float e = __expf(2.f * acc);
    part[w][0][lane] = 1.f - 2.f / (e + 1.f);   // after all part reads (lockstep wave)

    const float* hrow = &part[w][0][0];
    float tf = 0.f;
#pragma unroll
    for (int k4 = 0; k4 < 16; ++k4) {
        float4 hv = *(const float4*)(hrow + k4 * 4);   // broadcast
        float4 wv = W2t4[k4 * 64 + lane];
        tf += hv.x * wv.x + hv.y * wv.y + hv.z * wv.z + hv.w * wv.w;
    }
    T2[(size_t)node * DIM + lane] = f2bf(tf);

    // zero T2's dummy pad row (block 0 only; agg2 gathers it for padding)
    if (blockIdx.x == 0 && tid < 64)
        T2[(size_t)N_NODES * DIM + tid] = 0;
}

// R17-proven agg_out with plain idx/nodeinfo loads (R23). No barrier.
__global__ __launch_bounds__(512) void agg_out(const unsigned short* __restrict__ T,
                                               const unsigned short* __restrict__ csr,
                                               const unsigned* __restrict__ nodeinfo,
                                               const float* __restrict__ bias,
                                               float* __restrict__ outp) {
    __shared__ __align__(16) float part[8][8][72];  // 18 KB, wave-private
    int tid = threadIdx.x;
    int w = tid >> 6;
    int lane = tid & 63;
    int g8 = lane >> 3;
    int fs = lane & 7;
    int node = blockIdx.x * 8 + w;   // grid*8 == 50000 exactly

    unsigned info = nodeinfo[node];
    float bv = bias[lane];
    int pos = (int)(info & 0x7FFFFFu);
    int nch = (int)(info >> 23) >> 3;
    const unsigned short* ip = csr + pos + g8;
    const uint4* Tp = (const uint4*)T;
    float a0 = 0.f, a1 = 0.f, a2 = 0.f, a3 = 0.f, a4 = 0.f, a5 = 0.f, a6 = 0.f, a7 = 0.f;
    int c = 0;
    for (; c + 4 <= nch; c += 4) {
        int j0 = ip[c * 8];
        int j1 = ip[c * 8 + 8];
        int j2 = ip[c * 8 + 16];
        int j3 = ip[c * 8 + 24];
        uint4 d0 = Tp[j0 * 8 + fs];
        uint4 d1 = Tp[j1 * 8 + fs];
        uint4 d2 = Tp[j2 * 8 + fs];
        uint4 d3 = Tp[j3 * 8 + fs];
        ACC8(d0) ACC8(d1) ACC8(d2) ACC8(d3)
    }
    if (c < nch) {
        int j0 = ip[c * 8];
        int j1 = ip[c * 8 + 8];
        uint4 d0 = Tp[j0 * 8 + fs];
        uint4 d1 = Tp[j1 * 8 + fs];
        ACC8(d0) ACC8(d1)
    }
    float4 pa = {a0, a1, a2, a3};
    float4 pb = {a4, a5, a6, a7};
    *(float4*)&part[w][g8][fs * 8] = pa;
    *(float4*)&part[w][g8][fs * 8 + 4] = pb;
    // part is wave-private: wave-internal DS ordering suffices, no barrier

    float acc = bv;
#pragma unroll
    for (int g = 0; g < 8; ++g) acc += part[w][g][lane];
    __builtin_nontemporal_store(acc, outp + (size_t)node * DIM + lane);
}

extern "C" void kernel_launch(void* const* d_in, const int* in_sizes, int n_in,
                              void* d_out, int out_size, void* d_ws, size_t ws_size,
                              hipStream_t stream) {
    const float* feat = (const float*)d_in[0];
    const int*   src  = (const int*)d_in[1];
    const int*   dst  = (const int*)d_in[2];
    const float* W1   = (const float*)d_in[3];
    const float* b1   = (const float*)d_in[4];
    const float* W2   = (const float*)d_in[5];
    const float* b2   = (const float*)d_in[6];
    float* out = (float*)d_out;

    // ws layout (~29 MB; harness poisons 256 MB of ws -> plenty)
    int*            binned   = (int*)d_ws;                                 // 196*12288 ints
    unsigned short* csr16    = (unsigned short*)(binned + NBK * CSR_CAP);  // 196*13312 ushort
    unsigned*       nodeinfo = (unsigned*)(csr16 + NBK * BCAP);            // 50000
    int*            bcur     = (int*)(nodeinfo + N_NODES);                 // 196*8*16 ints
    unsigned short* t        = (unsigned short*)(bcur + NBK * 8 * 16 + 8); // 50001*64 bf16
    unsigned short* t2       = t + (size_t)(N_NODES + 1) * 64;             // 50001*64 bf16

    // ---- binning + layer-1 transform (fused), CSR build ----
    (void)hipMemsetAsync(bcur, 0, NBK * 8 * 16 * sizeof(int), stream);
    bin_gemm1<<<BIN_BLOCKS + G1_BLOCKS, 256, 0, stream>>>(
        src, dst, bcur, binned, feat, W1, t);
    build_csr<<<NBK, 256, 0, stream>>>(binned, bcur, nodeinfo, csr16);

    // ---- Layer 1 aggregate + fused layer-2 transform: t2 = tanh(agg+b1)@W2^T ----
    agg_fuse1<<<NB_AGG8, 512, 0, stream>>>(t, csr16, nodeinfo, b1, W2, t2);

    // ---- Layer 2 aggregate: out = agg(t2) + b2, f32 ----
    agg_out<<<NB_AGG8, 512, 0, stream>>>(t2, csr16, nodeinfo, b2, out);
}

// Round 11
// 207.205 us; speedup vs baseline: 1.2051x; 1.0620x over previous
//
#include <hip/hip_runtime.h>

#define N_NODES 50000
#define N_EDGES 1600000
#define DIM 64
#define NBK 196          // buckets of 256 dst-nodes
#define BIN_BLOCKS 391   // ceil(1.6M / 4096)
#define CSR_CAP 12288    // per-bucket binned slots = 8 octants x OCT_CAP
#define OCT_CAP 1536     // per-(bucket,octant) slots (mean ~1021, +16 sigma)
#define BCAP 13312       // per-bucket csr16 slots (mean 8192 + pad<=3840 + 14-sigma)
#define G1_BLOCKS 391    // gemm1 half: 391*128 = 50048 >= 50001 nodes (incl. dummy)
#define NB_AGG8 6250     // agg blocks (8 nodes/block; 6250*8 == 50000 exactly)

// f32 -> bf16 round-to-nearest-even
__device__ __forceinline__ unsigned short f2bf(float f) {
    union { float f; unsigned u; } v; v.f = f;
    unsigned r = v.u + 0x7FFF + ((v.u >> 16) & 1);
    return (unsigned short)(r >> 16);
}
__device__ __forceinline__ float bf2f(unsigned short h) {
    union { unsigned u; float f; } v; v.u = ((unsigned)h) << 16;  return v.f;
}
// packed-bf16 halves of a uint -> f32 (low ushort, high ushort)
__device__ __forceinline__ float blo(unsigned u) {
    union { unsigned u; float f; } v; v.u = u << 16; return v.f;
}
__device__ __forceinline__ float bhi(unsigned u) {
    union { unsigned u; float f; } v; v.u = u & 0xFFFF0000u; return v.f;
}

// R24: fused binning + GEMM1. Binning edge loop is PHASE-SPLIT: all 32
// global loads issue first (independent, in flight together), THEN the LDS
// atomics run. R23's interleaved loop serialized as load(900cy)->atomic x16
// because the compiler won't hoist loads across side-effecting atomics --
// that chain, not atomics/BW/occupancy (R20/R22 nulls), is the ~45us theory.
__global__ __launch_bounds__(256) void bin_gemm1(const int* __restrict__ src,
                                                 const int* __restrict__ dst,
                                                 int* __restrict__ bcur,
                                                 int* __restrict__ binned,
                                                 const float* __restrict__ X,
                                                 const float* __restrict__ W,
                                                 unsigned short* __restrict__ T) {
    __shared__ __align__(16) char smem[32768];
    int tid = threadIdx.x;

    if (blockIdx.x >= BIN_BLOCKS) {
        // ---------------- GEMM path (R21-proven): T = X @ W^T ----------------
        float4* xs = (float4*)smem;      // 128 node rows x 16 float4 = 32KB
        int w = tid >> 6, lane = tid & 63;
        int nbase = (blockIdx.x - BIN_BLOCKS) * 128;

        float4 wreg[16];
        const float4* wp = (const float4*)(W + lane * 64);
#pragma unroll
        for (int k4 = 0; k4 < 16; ++k4) wreg[k4] = wp[k4];

        const float4* xg = (const float4*)X;
        for (int L = tid; L < 2048; L += 256) {
            int row = nbase + (L >> 4);
            float4 v = {0.f, 0.f, 0.f, 0.f};
            if (row < N_NODES) v = xg[(size_t)row * 16 + (L & 15)];
            xs[L] = v;
        }
        __syncthreads();

        for (int g = 0; g < 8; ++g) {
            int n0 = w * 32 + g * 4;
            float accA = 0.f, accB = 0.f, accC = 0.f, accD = 0.f;
#pragma unroll
            for (int k4 = 0; k4 < 16; ++k4) {
                float4 w4 = wreg[k4];
                float4 xA = xs[(n0 + 0) * 16 + k4];   // wave-uniform -> broadcast
                float4 xB = xs[(n0 + 1) * 16 + k4];
                float4 xC = xs[(n0 + 2) * 16 + k4];
                float4 xD = xs[(n0 + 3) * 16 + k4];
                accA += xA.x * w4.x + xA.y * w4.y + xA.z * w4.z + xA.w * w4.w;
                accB += xB.x * w4.x + xB.y * w4.y + xB.z * w4.z + xB.w * w4.w;
                accC += xC.x * w4.x + xC.y * w4.y + xC.z * w4.z + xC.w * w4.w;
                accD += xD.x * w4.x + xD.y * w4.y + xD.z * w4.z + xD.w * w4.w;
            }
            int gn = nbase + n0;
            unsigned short vA = (gn + 0 == N_NODES) ? (unsigned short)0 : f2bf(accA);
            unsigned short vB = (gn + 1 == N_NODES) ? (unsigned short)0 : f2bf(accB);
            unsigned short vC = (gn + 2 == N_NODES) ? (unsigned short)0 : f2bf(accC);
            unsigned short vD = (gn + 3 == N_NODES) ? (unsigned short)0 : f2bf(accD);
            if (gn + 0 <= N_NODES) T[(size_t)(gn + 0) * 64 + lane] = vA;
            if (gn + 1 <= N_NODES) T[(size_t)(gn + 1) * 64 + lane] = vB;
            if (gn + 2 <= N_NODES) T[(size_t)(gn + 2) * 64 + lane] = vC;
            if (gn + 3 <= N_NODES) T[(size_t)(gn + 3) * 64 + lane] = vD;
        }
        return;
    }

    // ---------------- Binning path (R6 core, R24 phase-split loads) ----------------
    int* cnt    = (int*)smem;            // 256 ints (NBK used)
    int* lofs   = cnt + 256;
    int* shiftv = lofs + 256;
    int* sb     = shiftv + 256;
    int* stag   = sb + 256;              // 4096 ints = 16KB
    unsigned char* stb = (unsigned char*)(stag + 4096);  // 4096B

    if (tid < NBK) cnt[tid] = 0;
    __syncthreads();

    int base = blockIdx.x * 4096;
    int oct = blockIdx.x & 7;
    int nedge = N_EDGES - base;
    if (nedge > 4096) nedge = 4096;

    // Phase 1: pure load loop -- 32 independent global loads, all in flight.
    int sreg[16], dreg[16];
#pragma unroll
    for (int i = 0; i < 16; ++i) {
        int e = base + i * 256 + tid;
        if (e < N_EDGES) { sreg[i] = src[e]; dreg[i] = dst[e]; }
        else             { sreg[i] = 0;      dreg[i] = -1; }
    }
    // Phase 2: LDS histogram with rank (no loads in this loop).
    int myr[16];
#pragma unroll
    for (int i = 0; i < 16; ++i)
        if (dreg[i] >= 0) myr[i] = atomicAdd(&cnt[dreg[i] >> 8], 1);
    __syncthreads();

    int c = (tid < NBK) ? cnt[tid] : 0;
    sb[tid] = c;
    __syncthreads();
    for (int off = 1; off < 256; off <<= 1) {
        int u = (tid >= off) ? sb[tid - off] : 0;
        __syncthreads();
        sb[tid] += u;
        __syncthreads();
    }
    if (tid < NBK) {
        lofs[tid] = sb[tid] - c;
        if (c) shiftv[tid] = tid * CSR_CAP + oct * OCT_CAP
                           + atomicAdd(&bcur[(tid * 8 + oct) * 16], c) - lofs[tid];
    }
    __syncthreads();

#pragma unroll
    for (int i = 0; i < 16; ++i) {
        if (dreg[i] >= 0) {
            int b = dreg[i] >> 8;
            int idx = lofs[b] + myr[i];
            stag[idx] = ((dreg[i] & 255) << 16) | sreg[i];
            stb[idx] = (unsigned char)b;
        }
    }
    __syncthreads();

    for (int i = tid; i < nedge; i += 256)
        binned[i + shiftv[stb[i]]] = stag[i];
}

// R23 single-pass build_csr + R24 depth-4 prefetch in both scans (breaks the
// load->atomic serial chain the same way as the bin path).
__global__ __launch_bounds__(256) void build_csr(const int* __restrict__ binned,
                                                 const int* __restrict__ bcur,
                                                 unsigned* __restrict__ nodeinfo,
                                                 unsigned short* __restrict__ csr16) {
    __shared__ int cnt[256], cnt2[256], ofs[256], sb[256];
    __shared__ int mo[8];
    int tid = threadIdx.x;
    int b = blockIdx.x;
    int bbase = b * BCAP;
    cnt[tid] = 0; cnt2[tid] = 0;
    if (tid < 8) {
        int m = bcur[(b * 8 + tid) * 16];
        mo[tid] = m > OCT_CAP ? OCT_CAP : m;
    }
    __syncthreads();

    for (int oct = 0; oct < 8; ++oct) {
        const int* ib = binned + b * CSR_CAP + oct * OCT_CAP;
        int m = mo[oct];
        int i = tid;
        for (; i + 768 < m; i += 1024) {
            int p0 = ib[i], p1 = ib[i + 256], p2 = ib[i + 512], p3 = ib[i + 768];
            atomicAdd(&cnt[(p0 >> 16) & 255], 1);
            atomicAdd(&cnt[(p1 >> 16) & 255], 1);
            atomicAdd(&cnt[(p2 >> 16) & 255], 1);
            atomicAdd(&cnt[(p3 >> 16) & 255], 1);
        }
        for (; i < m; i += 256)
            atomicAdd(&cnt[(ib[i] >> 16) & 255], 1);
    }
    __syncthreads();

    int myc = cnt[tid];
    int v = (myc + 15) & ~15;          // mult-16 pad
    sb[tid] = v;
    __syncthreads();
    for (int off = 1; off < 256; off <<= 1) {
        int u = (tid >= off) ? sb[tid - off] : 0;
        __syncthreads();
        sb[tid] += u;
        __syncthreads();
    }
    int o = sb[tid] - v;
    ofs[tid] = o;
    int node = (b << 8) + tid;
    if (node < N_NODES)
        nodeinfo[node] = ((unsigned)v << 23) | (unsigned)(bbase + o);
    for (int i = myc; i < v; ++i)       // pad tail with dummy src
        csr16[bbase + o + i] = (unsigned short)N_NODES;
    __syncthreads();

    for (int oct = 0; oct < 8; ++oct) {
        const int* ib = binned + b * CSR_CAP + oct * OCT_CAP;
        int m = mo[oct];
        int i = tid;
        for (; i + 768 < m; i += 1024) {
            int p0 = ib[i], p1 = ib[i + 256], p2 = ib[i + 512], p3 = ib[i + 768];
            int d0 = (p0 >> 16) & 255, d1 = (p1 >> 16) & 255;
            int d2 = (p2 >> 16) & 255, d3 = (p3 >> 16) & 255;
            int r0 = atomicAdd(&cnt2[d0], 1);
            int r1 = atomicAdd(&cnt2[d1], 1);
            int r2 = atomicAdd(&cnt2[d2], 1);
            int r3 = atomicAdd(&cnt2[d3], 1);
            csr16[bbase + ofs[d0] + r0] = (unsigned short)(p0 & 0xFFFF);
            csr16[bbase + ofs[d1] + r1] = (unsigned short)(p1 & 0xFFFF);
            csr16[bbase + ofs[d2] + r2] = (unsigned short)(p2 & 0xFFFF);
            csr16[bbase + ofs[d3] + r3] = (unsigned short)(p3 & 0xFFFF);
        }
        for (; i < m; i += 256) {
            int p = ib[i];
            int dl = (p >> 16) & 255;
            int r = atomicAdd(&cnt2[dl], 1);
            csr16[bbase + ofs[dl] + r] = (unsigned short)(p & 0xFFFF);
        }
    }
}

// Accumulate one uint4 (8 bf16 feature values) into 8 f32 accumulators.
#define ACC8(d)                                                     \
    a0 += blo(d.x); a1 += bhi(d.x); a2 += blo(d.y); a3 += bhi(d.y); \
    a4 += blo(d.z); a5 += bhi(d.z); a6 += blo(d.w); a7 += bhi(d.w);

// R23-verbatim agg_fuse1 (at the 2-sector/edge TCP floor -- R17/R19/R22
// proved hit-tier/occupancy invariance). Plain idx loads.
__global__ __launch_bounds__(512) void agg_fuse1(const unsigned short* __restrict__ T,
                                                 const unsigned short* __restrict__ csr,
                                                 const unsigned* __restrict__ nodeinfo,
                                                 const float* __restrict__ b1,
                                                 const float* __restrict__ W2,
                                                 unsigned short* __restrict__ T2) {
    __shared__ __align__(16) float4 W2t4[1024];     // 16 KB (W2 transposed, lane-striped)
    __shared__ __align__(16) float part[8][8][72];  // 18 KB (per-wave partials; row0 doubles as h)
    int tid = threadIdx.x;
    int w = tid >> 6;
    int lane = tid & 63;
    int g8 = lane >> 3;
    int fs = lane & 7;
    int node = blockIdx.x * 8 + w;

    for (int L4 = tid; L4 < 1024; L4 += 512) {
        int k4 = L4 >> 6, f = L4 & 63;
        W2t4[L4] = *(const float4*)(W2 + f * 64 + k4 * 4);
    }

    unsigned info = nodeinfo[node];
    float bias = b1[lane];
    int pos = (int)(info & 0x7FFFFFu);
    int nch = (int)(info >> 23) >> 3;   // 8-edge chunks, even (pcnt mult 16)
    const unsigned short* ip = csr + pos + g8;
    const uint4* Tp = (const uint4*)T;
    float a0 = 0.f, a1 = 0.f, a2 = 0.f, a3 = 0.f, a4 = 0.f, a5 = 0.f, a6 = 0.f, a7 = 0.f;
    int c = 0;
    for (; c + 4 <= nch; c += 4) {
        int j0 = ip[c * 8];
        int j1 = ip[c * 8 + 8];
        int j2 = ip[c * 8 + 16];
        int j3 = ip[c * 8 + 24];
        uint4 d0 = Tp[j0 * 8 + fs];
        uint4 d1 = Tp[j1 * 8 + fs];
        uint4 d2 = Tp[j2 * 8 + fs];
        uint4 d3 = Tp[j3 * 8 + fs];
        ACC8(d0) ACC8(d1) ACC8(d2) ACC8(d3)
    }
    if (c < nch) {   // remaining 2 chunks (nch even)
        int j0 = ip[c * 8];
        int j1 = ip[c * 8 + 8];
        uint4 d0 = Tp[j0 * 8 + fs];
        uint4 d1 = Tp[j1 * 8 + fs];
        ACC8(d0) ACC8(d1)
    }
    float4 pa = {a0, a1, a2, a3};
    float4 pb = {a4, a5, a6, a7};
    *(float4*)&part[w][g8][fs * 8] = pa;
    *(float4*)&part[w][g8][fs * 8 + 4] = pb;
    __syncthreads();   // covers W2t4 staging (part is wave-private)

    float acc = bias;
#pragma unroll
    for (int g = 0; g < 8; ++g) acc += part[w][g][lane];

    float e = __expf(2.f * acc);
    part[w][0][lane] = 1.f - 2.f / (e + 1.f);   // after all part reads (lockstep wave)

    const float* hrow = &part[w][0][0];
    float tf = 0.f;
#pragma unroll
    for (int k4 = 0; k4 < 16; ++k4) {
        float4 hv = *(const float4*)(hrow + k4 * 4);   // broadcast
        float4 wv = W2t4[k4 * 64 + lane];
        tf += hv.x * wv.x + hv.y * wv.y + hv.z * wv.z + hv.w * wv.w;
    }
    T2[(size_t)node * DIM + lane] = f2bf(tf);

    // zero T2's dummy pad row (block 0 only; agg2 gathers it for padding)
    if (blockIdx.x == 0 && tid < 64)
        T2[(size_t)N_NODES * DIM + tid] = 0;
}

// R23-verbatim agg_out (2-sector/edge floor). Plain idx loads. No barrier.
__global__ __launch_bounds__(512) void agg_out(const unsigned short* __restrict__ T,
                                               const unsigned short* __restrict__ csr,
                                               const unsigned* __restrict__ nodeinfo,
                                               const float* __restrict__ bias,
                                               float* __restrict__ outp) {
    __shared__ __align__(16) float part[8][8][72];  // 18 KB, wave-private
    int tid = threadIdx.x;
    int w = tid >> 6;
    int lane = tid & 63;
    int g8 = lane >> 3;
    int fs = lane & 7;
    int node = blockIdx.x * 8 + w;   // grid*8 == 50000 exactly

    unsigned info = nodeinfo[node];
    float bv = bias[lane];
    int pos = (int)(info & 0x7FFFFFu);
    int nch = (int)(info >> 23) >> 3;
    const unsigned short* ip = csr + pos + g8;
    const uint4* Tp = (const uint4*)T;
    float a0 = 0.f, a1 = 0.f, a2 = 0.f, a3 = 0.f, a4 = 0.f, a5 = 0.f, a6 = 0.f, a7 = 0.f;
    int c = 0;
    for (; c + 4 <= nch; c += 4) {
        int j0 = ip[c * 8];
        int j1 = ip[c * 8 + 8];
        int j2 = ip[c * 8 + 16];
        int j3 = ip[c * 8 + 24];
        uint4 d0 = Tp[j0 * 8 + fs];
        uint4 d1 = Tp[j1 * 8 + fs];
        uint4 d2 = Tp[j2 * 8 + fs];
        uint4 d3 = Tp[j3 * 8 + fs];
        ACC8(d0) ACC8(d1) ACC8(d2) ACC8(d3)
    }
    if (c < nch) {
        int j0 = ip[c * 8];
        int j1 = ip[c * 8 + 8];
        uint4 d0 = Tp[j0 * 8 + fs];
        uint4 d1 = Tp[j1 * 8 + fs];
        ACC8(d0) ACC8(d1)
    }
    float4 pa = {a0, a1, a2, a3};
    float4 pb = {a4, a5, a6, a7};
    *(float4*)&part[w][g8][fs * 8] = pa;
    *(float4*)&part[w][g8][fs * 8 + 4] = pb;
    // part is wave-private: wave-internal DS ordering suffices, no barrier

    float acc = bv;
#pragma unroll
    for (int g = 0; g < 8; ++g) acc += part[w][g][lane];
    __builtin_nontemporal_store(acc, outp + (size_t)node * DIM + lane);
}

extern "C" void kernel_launch(void* const* d_in, const int* in_sizes, int n_in,
                              void* d_out, int out_size, void* d_ws, size_t ws_size,
                              hipStream_t stream) {
    const float* feat = (const float*)d_in[0];
    const int*   src  = (const int*)d_in[1];
    const int*   dst  = (const int*)d_in[2];
    const float* W1   = (const float*)d_in[3];
    const float* b1   = (const float*)d_in[4];
    const float* W2   = (const float*)d_in[5];
    const float* b2   = (const float*)d_in[6];
    float* out = (float*)d_out;

    // ws layout (~29 MB; harness poisons 256 MB of ws -> plenty)
    int*            binned   = (int*)d_ws;                                 // 196*12288 ints
    unsigned short* csr16    = (unsigned short*)(binned + NBK * CSR_CAP);  // 196*13312 ushort
    unsigned*       nodeinfo = (unsigned*)(csr16 + NBK * BCAP);            // 50000
    int*            bcur     = (int*)(nodeinfo + N_NODES);                 // 196*8*16 ints
    unsigned short* t        = (unsigned short*)(bcur + NBK * 8 * 16 + 8); // 50001*64 bf16
    unsigned short* t2       = t + (size_t)(N_NODES + 1) * 64;             // 50001*64 bf16

    // ---- binning + layer-1 transform (fused), CSR build ----
    (void)hipMemsetAsync(bcur, 0, NBK * 8 * 16 * sizeof(int), stream);
    bin_gemm1<<<BIN_BLOCKS + G1_BLOCKS, 256, 0, stream>>>(
        src, dst, bcur, binned, feat, W1, t);
    build_csr<<<NBK, 256, 0, stream>>>(binned, bcur, nodeinfo, csr16);

    // ---- Layer 1 aggregate + fused layer-2 transform: t2 = tanh(agg+b1)@W2^T ----
    agg_fuse1<<<NB_AGG8, 512, 0, stream>>>(t, csr16, nodeinfo, b1, W2, t2);

    // ---- Layer 2 aggregate: out = agg(t2) + b2, f32 ----
    agg_out<<<NB_AGG8, 512, 0, stream>>>(t2, csr16, nodeinfo, b2, out);
}